// Round 8
// baseline (152.570 us; speedup 1.0000x reference)
//
#include <hip/hip_runtime.h>
#include <hip/hip_fp16.h>

typedef _Float16 f16x8  __attribute__((ext_vector_type(8)));
typedef _Float16 f16x4  __attribute__((ext_vector_type(4)));
typedef float    f32x16 __attribute__((ext_vector_type(16)));

constexpr int Nn = 8192;
constexpr int Dd = 256;

constexpr int BM = 256;        // I-rows per block
constexpr int KC = 1024;       // K range per block
constexpr int SK = 32;         // staged K subchunk
constexpr int NSC = KC / SK;   // 32 subchunks
constexpr int ABUF = BM * SK;  // 8192 f16 = 16 KB per buffer
constexpr int YBUF = Dd * SK;  // 8192 f16 = 16 KB per buffer

// ---------------------------------------------------------------------------
// K1: row sums of A -> dis[i] = rsqrt(sum+1e-10), rd[i] = sqrt(sum+1e-10).
//     ALSO converts A to f16 (Af16, 128 MB) so pass 2 reads half the bytes and
//     can hit L3 (128 MB < 256 MB Infinity Cache). Conversion is the same RTN
//     v_cvt k_main used in-register -> numerics identical to round 7.
__global__ __launch_bounds__(256) void k_rowcvt(const float* __restrict__ A,
                                                _Float16* __restrict__ Af16,
                                                float* __restrict__ dis,
                                                float* __restrict__ rd,
                                                float* __restrict__ T) {
    if (blockIdx.x == 0 && threadIdx.x == 0) *T = 0.f;
    const int row  = blockIdx.x * 4 + (threadIdx.x >> 6);
    const int lane = threadIdx.x & 63;
    const float4* rp = reinterpret_cast<const float4*>(A + (size_t)row * Nn);
    f16x4* wp = reinterpret_cast<f16x4*>(Af16 + (size_t)row * Nn);
    float s = 0.f;
    #pragma unroll
    for (int i = 0; i < Nn / 256; ++i) {
        float4 v = rp[i * 64 + lane];
        s += (v.x + v.y) + (v.z + v.w);
        wp[i * 64 + lane] = f16x4{ (_Float16)v.x, (_Float16)v.y,
                                   (_Float16)v.z, (_Float16)v.w };
    }
    #pragma unroll
    for (int off = 32; off > 0; off >>= 1) s += __shfl_down(s, off, 64);
    if (lane == 0) {
        float rs = s + 1e-10f;
        dis[row] = rsqrtf(rs);
        rd[row]  = sqrtf(rs);
    }
}

// ---------------------------------------------------------------------------
// K2: Y = dis * Z/||Z||; store Yt[256 n][8192 i] (k-major) and Yr[8192][256]
__global__ __launch_bounds__(256) void k_makeYt(const float* __restrict__ Z,
                                               const float* __restrict__ dis,
                                               _Float16* __restrict__ Yt,
                                               _Float16* __restrict__ Yr) {
    __shared__ float nrm[64][4];
    __shared__ _Float16 tile[Dd][72];
    const int t = threadIdx.x;
    const int r = t >> 2, q = t & 3;
    const int row = blockIdx.x * 64 + r;
    const float4* zp = reinterpret_cast<const float4*>(Z + (size_t)row * Dd + q * 64);
    float4 v[16];
    float ss = 0.f;
    #pragma unroll
    for (int i = 0; i < 16; ++i) {
        v[i] = zp[i];
        ss += v[i].x*v[i].x + v[i].y*v[i].y + v[i].z*v[i].z + v[i].w*v[i].w;
    }
    nrm[r][q] = ss;
    __syncthreads();
    const float tot   = nrm[r][0] + nrm[r][1] + nrm[r][2] + nrm[r][3];
    const float scale = dis[row] / fmaxf(sqrtf(tot), 1e-12f);
    #pragma unroll
    for (int i = 0; i < 16; ++i) {
        const int c0 = q * 64 + i * 4;
        f16x4 y = { (_Float16)(v[i].x * scale), (_Float16)(v[i].y * scale),
                    (_Float16)(v[i].z * scale), (_Float16)(v[i].w * scale) };
        tile[c0+0][r] = y[0];
        tile[c0+1][r] = y[1];
        tile[c0+2][r] = y[2];
        tile[c0+3][r] = y[3];
        *reinterpret_cast<f16x4*>(Yr + (size_t)row * Dd + c0) = y;
    }
    __syncthreads();
    int4*       dst = reinterpret_cast<int4*>(Yt + (size_t)t * Nn + blockIdx.x * 64);
    const int4* src = reinterpret_cast<const int4*>(&tile[t][0]);
    #pragma unroll
    for (int i = 0; i < 8; ++i) dst[i] = src[i];
}

// ---------------------------------------------------------------------------
// K2b: s[k] = sum_j Zn[j][k] = sum_j Yt[k][j] * rd[j]
__global__ __launch_bounds__(256) void k_colsum(const _Float16* __restrict__ Yt,
                                                const float* __restrict__ rd,
                                                float* __restrict__ s) {
    const int k = blockIdx.x;
    const int t = threadIdx.x;
    const _Float16* yp = Yt + (size_t)k * Nn + t * 32;
    const float*    rp = rd + t * 32;
    float acc = 0.f;
    #pragma unroll
    for (int i = 0; i < 32; ++i) acc += (float)yp[i] * rp[i];
    #pragma unroll
    for (int off = 32; off > 0; off >>= 1) acc += __shfl_down(acc, off, 64);
    __shared__ float red[4];
    if ((t & 63) == 0) red[t >> 6] = acc;
    __syncthreads();
    if (t == 0) s[k] = red[0] + red[1] + red[2] + red[3];
}

// ---------------------------------------------------------------------------
// K3: T += sum_{i} Y_i . (Af16[I, Kchunk] @ Y[Kchunk])   [32x32x16 MFMA]
// Round-8: A read as f16 (halved bytes, 32 KB/iter total) -> HBM quota per
// iteration drops 4800->3200 cyc; Af16 should largely L3-hit. No in-loop CVT.
// ib DESCENDING (LIFO vs pass-1 write order) for L3 reuse; jb mapping as r7.
// Triple-buffered LDS: 3 x (16 KB A + 16 KB Yt) = 96 KB. Per iteration: wait
// vmcnt(2) [next subchunk's 2 DMA shots stay in flight], barrier, issue sc+2.
// MFMA 32x32x16_f16: A row=l&31, k=(l>>5)*8+e; B col=l&31 same k;
// D col=l&31, row=(reg&3)+8*(reg>>2)+4*(l>>5).
__global__ __launch_bounds__(1024, 4) void k_main(const _Float16* __restrict__ Af,
                                                  const _Float16* __restrict__ Yt,
                                                  const _Float16* __restrict__ Yr,
                                                  float* __restrict__ T) {
    __shared__ _Float16 As[3 * ABUF];    // 48 KB
    __shared__ _Float16 Ysm[3 * YBUF];   // 48 KB

    const int ib = (Nn / BM - 1) - (blockIdx.x & (Nn / BM - 1));  // descending
    const int jb = blockIdx.x >> 5;                               // 8 K-chunks
    const int I0 = ib * BM;
    const int K0 = jb * KC;
    const int t   = threadIdx.x;
    const int w   = t >> 6;            // 0..15
    const int wm  = w >> 1;            // 32-row stripe (0..7)
    const int wn  = w & 1;             // 128-col half
    const int l   = t & 63;
    const int ln  = l & 31;
    const int lkh = l >> 5;

    f32x16 acc[4];
    #pragma unroll
    for (int q = 0; q < 4; ++q) acc[q] = (f32x16)(0.f);

    // Stage subchunk SC into buffer B: 1 A-shot + 1 Yt-shot (16 KB each).
    // Linear LDS dest (wave base + lane*16); source slot pre-swizzled:
    //   A:  LDS[row][slot] holds global slot slot^(row&3)   (row = w*16+(l>>2))
    //   Yt: LDS[n][slot]   holds global slot slot^(n&3)     (n   = w*16+(l>>2))
    #define STAGE(SC, B)                                                       \
    {   const int kc = SC == 0 ? K0 : K0 + (SC) * SK;                          \
        const int rr = w * 16 + (l >> 2);                                      \
        const int sl = (l & 3) ^ ((l >> 2) & 3);                               \
        __builtin_amdgcn_global_load_lds(                                      \
            (const __attribute__((address_space(1))) unsigned int*)            \
                (Af + (size_t)(I0 + rr) * Nn + kc + sl * 8),                   \
            (__attribute__((address_space(3))) unsigned int*)                  \
                (As + (B) * ABUF + (w * 16) * SK),                             \
            16, 0, 0);                                                         \
        __builtin_amdgcn_global_load_lds(                                      \
            (const __attribute__((address_space(1))) unsigned int*)            \
                (Yt + (size_t)rr * Nn + kc + sl * 8),                          \
            (__attribute__((address_space(3))) unsigned int*)                  \
                (Ysm + (B) * YBUF + (w * 16) * SK),                            \
            16, 0, 0);                                                         \
    }

    STAGE(0, 0);
    STAGE(1, 1);

    for (int sc = 0; sc < NSC; ++sc) {
        if (sc + 1 < NSC) { asm volatile("s_waitcnt vmcnt(2)" ::: "memory"); }
        else              { asm volatile("s_waitcnt vmcnt(0)" ::: "memory"); }
        __builtin_amdgcn_s_barrier();
        if (sc + 2 < NSC) STAGE(sc + 2, (sc + 2) % 3);

        const int cb = sc % 3;
        const _Float16* Ab = As  + cb * ABUF + (wm * 32 + ln) * SK;
        const _Float16* Yb = Ysm + cb * YBUF;
        const int r3 = ln & 3;
        f16x8 af[2];
        #pragma unroll
        for (int ks = 0; ks < 2; ++ks) {
            const int s = (ks * 2 + lkh) ^ r3;
            af[ks] = *reinterpret_cast<const f16x8*>(Ab + s * 8);
        }
        #pragma unroll
        for (int tn = 0; tn < 4; ++tn) {
            const int n = wn * 128 + tn * 32 + ln;
            const _Float16* Yrow = Yb + n * SK;
            #pragma unroll
            for (int ks = 0; ks < 2; ++ks) {
                const int s = (ks * 2 + lkh) ^ (n & 3);
                const f16x8 bf = *reinterpret_cast<const f16x8*>(Yrow + s * 8);
                acc[tn] = __builtin_amdgcn_mfma_f32_32x32x16_f16(af[ks], bf, acc[tn], 0, 0, 0);
            }
        }
    }

    // epilogue: part = sum over held W[i][n] * Y[i][n]
    float part = 0.f;
    #pragma unroll
    for (int tn = 0; tn < 4; ++tn) {
        const int n = wn * 128 + tn * 32 + ln;
        #pragma unroll
        for (int r = 0; r < 16; ++r) {
            const int i = I0 + wm * 32 + (r & 3) + 8 * (r >> 2) + 4 * lkh;
            part += acc[tn][r] * (float)Yr[(size_t)i * Dd + n];
        }
    }
    #pragma unroll
    for (int off = 32; off > 0; off >>= 1) part += __shfl_down(part, off, 64);
    __shared__ float red[16];
    if (l == 0) red[w] = part;
    __syncthreads();
    if (threadIdx.x == 0) {
        float tt = 0.f;
        #pragma unroll
        for (int i = 0; i < 16; ++i) tt += red[i];
        atomicAdd(T, tt);
    }
}

// ---------------------------------------------------------------------------
// K4: out[0] = homo = -T ; out[1] = hetero = ||s||^2 - T
__global__ __launch_bounds__(256) void k_final(const float* __restrict__ s,
                                               const float* __restrict__ T,
                                               float* __restrict__ out) {
    const int t = threadIdx.x;
    float v = s[t];
    float p = v * v;
    #pragma unroll
    for (int off = 32; off > 0; off >>= 1) p += __shfl_down(p, off, 64);
    __shared__ float red[4];
    if ((t & 63) == 0) red[t >> 6] = p;
    __syncthreads();
    if (t == 0) {
        const float ss = red[0] + red[1] + red[2] + red[3];
        const float Tv = *T;
        out[0] = -Tv;
        out[1] = ss - Tv;
    }
}

// ---------------------------------------------------------------------------
extern "C" void kernel_launch(void* const* d_in, const int* in_sizes, int n_in,
                              void* d_out, int out_size, void* d_ws, size_t ws_size,
                              hipStream_t stream) {
    const float* Z = (const float*)d_in[1];
    const float* A = (const float*)d_in[2];
    float* out = (float*)d_out;

    char* ws = (char*)d_ws;
    float*    dis  = (float*)(ws);                     // 32 KB
    float*    rd   = (float*)(ws + 32768);             // 32 KB
    float*    s    = (float*)(ws + 65536);             // 1 KB
    float*    T    = (float*)(ws + 66560);             // 4 B
    _Float16* Yt   = (_Float16*)(ws + 131072);         // 4 MB  [256][8192]
    _Float16* Yr   = (_Float16*)(ws + 131072 + (size_t)Nn * Dd * 2);       // 4 MB
    _Float16* Af16 = (_Float16*)(ws + 131072 + (size_t)Nn * Dd * 4);       // 128 MB

    k_rowcvt<<<Nn / 4, 256, 0, stream>>>(A, Af16, dis, rd, T);
    k_makeYt<<<Nn / 64, 256, 0, stream>>>(Z, dis, Yt, Yr);
    k_colsum<<<Dd, 256, 0, stream>>>(Yt, rd, s);
    k_main<<<(Nn / BM) * (Nn / KC), 1024, 0, stream>>>(Af16, Yt, Yr, T);
    k_final<<<1, 256, 0, stream>>>(s, T, out);
}

// Round 9
// 142.878 us; speedup vs baseline: 1.0678x; 1.0678x over previous
//
#include <hip/hip_runtime.h>
#include <hip/hip_fp16.h>

typedef _Float16 f16x8  __attribute__((ext_vector_type(8)));
typedef _Float16 f16x4  __attribute__((ext_vector_type(4)));
typedef float    f32x16 __attribute__((ext_vector_type(16)));

constexpr int Nn = 8192;
constexpr int Dd = 256;

constexpr int BM  = 256;       // I-rows per block
constexpr int KC  = 1024;      // K range per block
constexpr int SK  = 16;        // staged K subchunk (small -> deep queue)
constexpr int NSC = KC / SK;   // 64 subchunks
constexpr int NB  = 6;         // LDS buffers (stage 5 ahead)
constexpr int ABUF = BM * SK;  // 4096 f32 = 16 KB
constexpr int YBUF = Dd * SK;  // 4096 f16 =  8 KB

// ---------------------------------------------------------------------------
// K1: row sums of A -> dis[i] = rsqrt(sum+1e-10), rd[i] = sqrt(sum+1e-10)
//     also zeroes the T accumulator (ws is poisoned 0xAA before timing).
__global__ __launch_bounds__(256) void k_rowsum(const float* __restrict__ A,
                                                float* __restrict__ dis,
                                                float* __restrict__ rd,
                                                float* __restrict__ T) {
    if (blockIdx.x == 0 && threadIdx.x == 0) *T = 0.f;
    const int row  = blockIdx.x * 4 + (threadIdx.x >> 6);
    const int lane = threadIdx.x & 63;
    const float4* rp = reinterpret_cast<const float4*>(A + (size_t)row * Nn);
    float s = 0.f;
    #pragma unroll
    for (int i = 0; i < Nn / 256; ++i) {
        float4 v = rp[i * 64 + lane];
        s += (v.x + v.y) + (v.z + v.w);
    }
    #pragma unroll
    for (int off = 32; off > 0; off >>= 1) s += __shfl_down(s, off, 64);
    if (lane == 0) {
        float rs = s + 1e-10f;
        dis[row] = rsqrtf(rs);
        rd[row]  = sqrtf(rs);
    }
}

// ---------------------------------------------------------------------------
// K2: Y = dis * Z/||Z||; store Yt[256 n][8192 i] (k-major) and Yr[8192][256]
__global__ __launch_bounds__(256) void k_makeYt(const float* __restrict__ Z,
                                               const float* __restrict__ dis,
                                               _Float16* __restrict__ Yt,
                                               _Float16* __restrict__ Yr) {
    __shared__ float nrm[64][4];
    __shared__ _Float16 tile[Dd][72];
    const int t = threadIdx.x;
    const int r = t >> 2, q = t & 3;
    const int row = blockIdx.x * 64 + r;
    const float4* zp = reinterpret_cast<const float4*>(Z + (size_t)row * Dd + q * 64);
    float4 v[16];
    float ss = 0.f;
    #pragma unroll
    for (int i = 0; i < 16; ++i) {
        v[i] = zp[i];
        ss += v[i].x*v[i].x + v[i].y*v[i].y + v[i].z*v[i].z + v[i].w*v[i].w;
    }
    nrm[r][q] = ss;
    __syncthreads();
    const float tot   = nrm[r][0] + nrm[r][1] + nrm[r][2] + nrm[r][3];
    const float scale = dis[row] / fmaxf(sqrtf(tot), 1e-12f);
    #pragma unroll
    for (int i = 0; i < 16; ++i) {
        const int c0 = q * 64 + i * 4;
        f16x4 y = { (_Float16)(v[i].x * scale), (_Float16)(v[i].y * scale),
                    (_Float16)(v[i].z * scale), (_Float16)(v[i].w * scale) };
        tile[c0+0][r] = y[0];
        tile[c0+1][r] = y[1];
        tile[c0+2][r] = y[2];
        tile[c0+3][r] = y[3];
        *reinterpret_cast<f16x4*>(Yr + (size_t)row * Dd + c0) = y;
    }
    __syncthreads();
    int4*       dst = reinterpret_cast<int4*>(Yt + (size_t)t * Nn + blockIdx.x * 64);
    const int4* src = reinterpret_cast<const int4*>(&tile[t][0]);
    #pragma unroll
    for (int i = 0; i < 8; ++i) dst[i] = src[i];
}

// ---------------------------------------------------------------------------
// K2b: s[k] = sum_j Zn[j][k] = sum_j Yt[k][j] * rd[j]
__global__ __launch_bounds__(256) void k_colsum(const _Float16* __restrict__ Yt,
                                                const float* __restrict__ rd,
                                                float* __restrict__ s) {
    const int k = blockIdx.x;
    const int t = threadIdx.x;
    const _Float16* yp = Yt + (size_t)k * Nn + t * 32;
    const float*    rp = rd + t * 32;
    float acc = 0.f;
    #pragma unroll
    for (int i = 0; i < 32; ++i) acc += (float)yp[i] * rp[i];
    #pragma unroll
    for (int off = 32; off > 0; off >>= 1) acc += __shfl_down(acc, off, 64);
    __shared__ float red[4];
    if ((t & 63) == 0) red[t >> 6] = acc;
    __syncthreads();
    if (t == 0) s[k] = red[0] + red[1] + red[2] + red[3];
}

// ---------------------------------------------------------------------------
// K3: T += sum_{i} Y_i . (A[I, Kchunk] @ Y[Kchunk])   [32x32x16 MFMA]
// Round-9: DEEP DMA QUEUE. SK=16 subchunks (24 KB: 16 KB f32 A + 8 KB Yt),
// 6 LDS buffers, stage 5 ahead -> ~120 KB always in flight per CU, so the
// HBM queue never drains (round-7's 18% idle tail). Per-wave counted vmcnt:
// waves 0-7 issue 2 shots/stage (A+Yt), waves 8-15 issue 1 (A).
// Swizzles (bank-verified, 8 dwords/bank): A LDS[row][sl] holds global slot
// sl^((row>>1)&3); Yt linear (32 B rows spread naturally).
// MFMA 32x32x16_f16: A row=l&31, k=(l>>5)*8+e; B col=l&31 same k;
// D col=l&31, row=(reg&3)+8*(reg>>2)+4*(l>>5).
__global__ __launch_bounds__(1024, 4) void k_main(const float* __restrict__ A,
                                                  const _Float16* __restrict__ Yt,
                                                  const _Float16* __restrict__ Yr,
                                                  float* __restrict__ T) {
    __shared__ float    As[NB * ABUF];    // 96 KB
    __shared__ _Float16 Ysm[NB * YBUF];   // 48 KB

    const int ib = blockIdx.x & (Nn / BM - 1);   // 32 I-tiles (fastest)
    const int jb = blockIdx.x >> 5;              // 8 K-chunks
    const int I0 = ib * BM;
    const int K0 = jb * KC;
    const int t   = threadIdx.x;
    const int w   = t >> 6;            // 0..15
    const int wm  = w >> 1;            // 32-row stripe (0..7)
    const int wn  = w & 1;             // 128-col half
    const int l   = t & 63;
    const int ln  = l & 31;
    const int lkh = l >> 5;

    f32x16 acc[4];
    #pragma unroll
    for (int q = 0; q < 4; ++q) acc[q] = (f32x16)(0.f);

    // Stage subchunk SC into buffer B. Per wave: 1 A-shot (16 rows x 16 f32);
    // waves 0-7 also 1 Yt-shot (32 n x 16 f16). Linear LDS dest
    // (wave-uniform base + lane*16); A source slot pre-swizzled.
    #define STAGE(SC, B)                                                       \
    {   const int kc = K0 + (SC) * SK;                                         \
        {   const int rr = w * 16 + (l >> 2);                                  \
            const int sl = (l & 3) ^ ((l >> 3) & 3);                           \
            __builtin_amdgcn_global_load_lds(                                  \
                (const __attribute__((address_space(1))) unsigned int*)        \
                    (A + (size_t)(I0 + rr) * Nn + kc + sl * 4),                \
                (__attribute__((address_space(3))) unsigned int*)              \
                    (As + (B) * ABUF + w * 256),                               \
                16, 0, 0);                                                     \
        }                                                                      \
        if (w < 8) {                                                           \
            const int nr = w * 32 + (l >> 1);                                  \
            __builtin_amdgcn_global_load_lds(                                  \
                (const __attribute__((address_space(1))) unsigned int*)        \
                    (Yt + (size_t)nr * Nn + kc + (l & 1) * 8),                 \
                (__attribute__((address_space(3))) unsigned int*)              \
                    (Ysm + (B) * YBUF + w * 512),                              \
                16, 0, 0);                                                     \
        }                                                                      \
    }

    #define WAITV(N) asm volatile("s_waitcnt vmcnt(" #N ")" ::: "memory")

    STAGE(0, 0); STAGE(1, 1); STAGE(2, 2); STAGE(3, 3); STAGE(4, 4);

    for (int sc = 0; sc < NSC; ++sc) {
        // outstanding stages at this point: min(4, NSC-1-sc) after the wait
        const int ah = NSC - 1 - sc;
        if (w < 8) {
            if (ah >= 4) WAITV(8); else if (ah == 3) WAITV(6);
            else if (ah == 2) WAITV(4); else if (ah == 1) WAITV(2); else WAITV(0);
        } else {
            if (ah >= 4) WAITV(4); else if (ah == 3) WAITV(3);
            else if (ah == 2) WAITV(2); else if (ah == 1) WAITV(1); else WAITV(0);
        }
        __builtin_amdgcn_s_barrier();
        if (sc + 5 < NSC) STAGE(sc + 5, (sc + 5) % NB);

        const int cb = sc % NB;
        const float*    Ab = As  + cb * ABUF + (wm * 32 + ln) * SK;
        const _Float16* Yb = Ysm + cb * YBUF;
        const int q = (ln >> 1) & 3;
        const float4 u0 = *reinterpret_cast<const float4*>(Ab + ((lkh * 2)     ^ q) * 4);
        const float4 u1 = *reinterpret_cast<const float4*>(Ab + ((lkh * 2 + 1) ^ q) * 4);
        const f16x8 af = { (_Float16)u0.x, (_Float16)u0.y, (_Float16)u0.z, (_Float16)u0.w,
                           (_Float16)u1.x, (_Float16)u1.y, (_Float16)u1.z, (_Float16)u1.w };
        #pragma unroll
        for (int tn = 0; tn < 4; ++tn) {
            const int n = wn * 128 + tn * 32 + ln;
            const f16x8 bf = *reinterpret_cast<const f16x8*>(Yb + n * SK + lkh * 8);
            acc[tn] = __builtin_amdgcn_mfma_f32_32x32x16_f16(af, bf, acc[tn], 0, 0, 0);
        }
    }

    // epilogue: part = sum over held W[i][n] * Y[i][n]
    float part = 0.f;
    #pragma unroll
    for (int tn = 0; tn < 4; ++tn) {
        const int n = wn * 128 + tn * 32 + ln;
        #pragma unroll
        for (int r = 0; r < 16; ++r) {
            const int i = I0 + wm * 32 + (r & 3) + 8 * (r >> 2) + 4 * lkh;
            part += acc[tn][r] * (float)Yr[(size_t)i * Dd + n];
        }
    }
    #pragma unroll
    for (int off = 32; off > 0; off >>= 1) part += __shfl_down(part, off, 64);
    __shared__ float red[16];
    if (l == 0) red[w] = part;
    __syncthreads();
    if (threadIdx.x == 0) {
        float tt = 0.f;
        #pragma unroll
        for (int i = 0; i < 16; ++i) tt += red[i];
        atomicAdd(T, tt);
    }
}

// ---------------------------------------------------------------------------
// K4: out[0] = homo = -T ; out[1] = hetero = ||s||^2 - T
__global__ __launch_bounds__(256) void k_final(const float* __restrict__ s,
                                               const float* __restrict__ T,
                                               float* __restrict__ out) {
    const int t = threadIdx.x;
    float v = s[t];
    float p = v * v;
    #pragma unroll
    for (int off = 32; off > 0; off >>= 1) p += __shfl_down(p, off, 64);
    __shared__ float red[4];
    if ((t & 63) == 0) red[t >> 6] = p;
    __syncthreads();
    if (t == 0) {
        const float ss = red[0] + red[1] + red[2] + red[3];
        const float Tv = *T;
        out[0] = -Tv;
        out[1] = ss - Tv;
    }
}

// ---------------------------------------------------------------------------
extern "C" void kernel_launch(void* const* d_in, const int* in_sizes, int n_in,
                              void* d_out, int out_size, void* d_ws, size_t ws_size,
                              hipStream_t stream) {
    const float* Z = (const float*)d_in[1];
    const float* A = (const float*)d_in[2];
    float* out = (float*)d_out;

    char* ws = (char*)d_ws;
    float*    dis = (float*)(ws);                      // 32 KB
    float*    rd  = (float*)(ws + 32768);              // 32 KB
    float*    s   = (float*)(ws + 65536);              // 1 KB
    float*    T   = (float*)(ws + 66560);              // 4 B
    _Float16* Yt  = (_Float16*)(ws + 131072);          // 4 MB  [256][8192]
    _Float16* Yr  = (_Float16*)(ws + 131072 + (size_t)Nn * Dd * 2);  // 4 MB [8192][256]

    k_rowsum<<<Nn / 4, 256, 0, stream>>>(A, dis, rd, T);
    k_makeYt<<<Nn / 64, 256, 0, stream>>>(Z, dis, Yt, Yr);
    k_colsum<<<Dd, 256, 0, stream>>>(Yt, rd, s);
    k_main<<<(Nn / BM) * (Nn / KC), 1024, 0, stream>>>(A, Yt, Yr, T);
    k_final<<<1, 256, 0, stream>>>(s, T, out);
}

// Round 10
// 126.540 us; speedup vs baseline: 1.2057x; 1.1291x over previous
//
#include <hip/hip_runtime.h>
#include <hip/hip_fp16.h>

typedef _Float16 f16x4  __attribute__((ext_vector_type(4)));
typedef float    f32x16 __attribute__((ext_vector_type(16)));

constexpr int Nn = 8192;
constexpr int Dd = 256;

constexpr int BM  = 256;        // I-rows per block
constexpr int KC  = 1024;       // K range per block
constexpr int SK  = 64;         // staged K subchunk (64 B/row = HBM granule)
constexpr int NSC = KC / SK;    // 16 subchunks
constexpr int NB  = 4;          // LDS buffers, stage 3 ahead
constexpr int ABYTES = BM * SK; // 16 KB per A buffer (fp8)
constexpr int YBYTES = Dd * SK; // 16 KB per Yt buffer (fp8)

#define AS1 __attribute__((address_space(1)))
#define AS3 __attribute__((address_space(3)))

// ---------------------------------------------------------------------------
// K1: rowsum of A -> dis = rsqrt(sum+1e-10), rd = sqrt(sum+1e-10);
//     ALSO writes Af8 = e4m3(A) (64 MB) for the fp8 pass 2.
//     Zeroes T and s (ws is poisoned 0xAA before timing).
__global__ __launch_bounds__(256) void k_rowcvt(const float* __restrict__ A,
                                                unsigned char* __restrict__ Af8,
                                                float* __restrict__ dis,
                                                float* __restrict__ rd,
                                                float* __restrict__ s,
                                                float* __restrict__ T) {
    if (blockIdx.x == 0) {
        if (threadIdx.x == 0) *T = 0.f;
        s[threadIdx.x] = 0.f;   // 256 threads cover s[0..255]
    }
    const int row  = blockIdx.x * 4 + (threadIdx.x >> 6);
    const int lane = threadIdx.x & 63;
    const float4*  rp = reinterpret_cast<const float4*>(A + (size_t)row * Nn);
    unsigned int*  wp = reinterpret_cast<unsigned int*>(Af8 + (size_t)row * Nn);
    float sum = 0.f;
    #pragma unroll
    for (int i = 0; i < Nn / 256; ++i) {
        float4 v = rp[i * 64 + lane];
        sum += (v.x + v.y) + (v.z + v.w);
        int p = __builtin_amdgcn_cvt_pk_fp8_f32(v.x, v.y, 0, false);
        p     = __builtin_amdgcn_cvt_pk_fp8_f32(v.z, v.w, p, true);
        wp[i * 64 + lane] = (unsigned int)p;
    }
    #pragma unroll
    for (int off = 32; off > 0; off >>= 1) sum += __shfl_down(sum, off, 64);
    if (lane == 0) {
        float rs = sum + 1e-10f;
        dis[row] = rsqrtf(rs);
        rd[row]  = sqrtf(rs);
    }
}

// ---------------------------------------------------------------------------
// K2: Y = dis * Z/||Z||. Writes Ytf8[256 n][8192 i] = e4m3(64*Y) (k-major,
//     GEMM B operand) and Yr[8192][256] f16 (true Y, for epilogue + colsum).
__global__ __launch_bounds__(256) void k_makeYt(const float* __restrict__ Z,
                                               const float* __restrict__ dis,
                                               unsigned char* __restrict__ Ytf8,
                                               _Float16* __restrict__ Yr) {
    __shared__ float nrm[64][4];
    __shared__ unsigned char tile[Dd][80];   // stride 80: 16B-aligned rows
    const int t = threadIdx.x;
    const int r = t >> 2, q = t & 3;
    const int row = blockIdx.x * 64 + r;
    const float4* zp = reinterpret_cast<const float4*>(Z + (size_t)row * Dd + q * 64);
    float4 v[16];
    float ss = 0.f;
    #pragma unroll
    for (int i = 0; i < 16; ++i) {
        v[i] = zp[i];
        ss += v[i].x*v[i].x + v[i].y*v[i].y + v[i].z*v[i].z + v[i].w*v[i].w;
    }
    nrm[r][q] = ss;
    __syncthreads();
    const float tot  = nrm[r][0] + nrm[r][1] + nrm[r][2] + nrm[r][3];
    const float sc   = dis[row] / fmaxf(sqrtf(tot), 1e-12f);   // true Y scale
    const float sc8  = 64.f * sc;                              // fp8 scale
    #pragma unroll
    for (int i = 0; i < 16; ++i) {
        const int c0 = q * 64 + i * 4;
        f16x4 y = { (_Float16)(v[i].x * sc), (_Float16)(v[i].y * sc),
                    (_Float16)(v[i].z * sc), (_Float16)(v[i].w * sc) };
        *reinterpret_cast<f16x4*>(Yr + (size_t)row * Dd + c0) = y;
        int p = __builtin_amdgcn_cvt_pk_fp8_f32(v[i].x * sc8, v[i].y * sc8, 0, false);
        p     = __builtin_amdgcn_cvt_pk_fp8_f32(v[i].z * sc8, v[i].w * sc8, p, true);
        tile[c0+0][r] = (unsigned char)(p);
        tile[c0+1][r] = (unsigned char)(p >> 8);
        tile[c0+2][r] = (unsigned char)(p >> 16);
        tile[c0+3][r] = (unsigned char)(p >> 24);
    }
    __syncthreads();
    int4*       dst = reinterpret_cast<int4*>(Ytf8 + (size_t)t * Nn + blockIdx.x * 64);
    const int4* src = reinterpret_cast<const int4*>(&tile[t][0]);
    #pragma unroll
    for (int i = 0; i < 4; ++i) dst[i] = src[i];
}

// ---------------------------------------------------------------------------
// K2b: s[k] = sum_j Zn[j][k] = sum_j Yr[j][k] * rd[j]   (f16 path, coalesced)
__global__ __launch_bounds__(256) void k_colsum(const _Float16* __restrict__ Yr,
                                                const float* __restrict__ rd,
                                                float* __restrict__ s) {
    const int c  = threadIdx.x;
    const int r0 = blockIdx.x * 256;
    float acc = 0.f;
    const _Float16* yp = Yr + (size_t)r0 * Dd + c;
    #pragma unroll 8
    for (int r = 0; r < 256; ++r) acc += (float)yp[(size_t)r * Dd] * rd[r0 + r];
    atomicAdd(&s[c], acc);
}

// ---------------------------------------------------------------------------
// K3: T += sum_i Y_i . (A[I,Kchunk] @ Y[Kchunk])   [32x32x16 fp8 MFMA]
// Round-10: both operands fp8 -> 128 MB total traffic (vs 396 MB r7).
// SK=64 (64 B/row = HBM granule), 4 buffers, stage 3 ahead, 2 shots/wave
// per stage -> uniform vmcnt(4). LDS 16B-preserving XOR swizzle
// (slot' = g ^ (((r>>1)&3)<<1)) hits the 4-dword/bank floor on b64 reads.
// fp8 32x32x16 fragments: A row=l&31, k=(l>>5)*8+byte; B col=l&31 same k;
// D col=l&31, row=(reg&3)+8*(reg>>2)+4*(l>>5) (shape-determined, m101).
// Yt holds 64*Y -> acc = 64*W; epilogue atomicAdd scales by 1/64.
__global__ __launch_bounds__(1024, 4) void k_main(const unsigned char* __restrict__ Af8,
                                                  const unsigned char* __restrict__ Ytf8,
                                                  const _Float16* __restrict__ Yr,
                                                  float* __restrict__ T) {
    __shared__ long As[NB * ABYTES / 8];    // 64 KB
    __shared__ long Ys[NB * YBYTES / 8];    // 64 KB
    char* As8 = (char*)As;
    char* Ys8 = (char*)Ys;

    const int ib = blockIdx.x & (Nn / BM - 1);   // 32 I-tiles (fastest)
    const int jb = blockIdx.x >> 5;              // 8 K-chunks
    const int I0 = ib * BM;
    const int K0 = jb * KC;
    const int t   = threadIdx.x;
    const int w   = t >> 6;            // 0..15
    const int wm  = w >> 1;            // 32-row stripe (0..7)
    const int wn  = w & 1;             // 128-col half
    const int l   = t & 63;
    const int ln  = l & 31;
    const int lkh = l >> 5;

    f32x16 acc[4];
    #pragma unroll
    for (int q = 0; q < 4; ++q) acc[q] = (f32x16)(0.f);

    // Stage subchunk SC into buffer B: per wave 1 A-shot + 1 Yt-shot (1 KB
    // each; 16 rows x 64 B). Linear LDS dest; source 16B-group pre-swizzled
    // by s ^ ((row>>1)&3) (matches the even-XOR read swizzle).
    #define STAGE(SC, B)                                                       \
    {   const int kc = K0 + (SC) * SK;                                         \
        const int rr = w * 16 + (l >> 2);                                      \
        const int sg = ((l & 3) ^ ((rr >> 1) & 3)) * 16;                       \
        __builtin_amdgcn_global_load_lds(                                      \
            (const AS1 unsigned int*)(Af8 + (size_t)(I0 + rr) * Nn + kc + sg), \
            (AS3 unsigned int*)(As8 + (B) * ABYTES + w * 1024), 16, 0, 0);     \
        __builtin_amdgcn_global_load_lds(                                      \
            (const AS1 unsigned int*)(Ytf8 + (size_t)rr * Nn + kc + sg),       \
            (AS3 unsigned int*)(Ys8 + (B) * YBYTES + w * 1024), 16, 0, 0);     \
    }

    #define WAITV(N) asm volatile("s_waitcnt vmcnt(" #N ")" ::: "memory")

    STAGE(0, 0); STAGE(1, 1); STAGE(2, 2);

    for (int sc = 0; sc < NSC; ++sc) {
        const int ah = NSC - 1 - sc;
        if (ah >= 2) WAITV(4); else if (ah == 1) WAITV(2); else WAITV(0);
        __builtin_amdgcn_s_barrier();
        if (sc + 3 < NSC) STAGE(sc + 3, (sc + 3) & 3);

        const int cb = sc & 3;
        const long* Al = reinterpret_cast<const long*>(As8 + cb * ABYTES);
        const long* Yl = reinterpret_cast<const long*>(Ys8 + cb * YBYTES);
        const int r  = wm * 32 + ln;
        const int xA = ((r >> 1) & 3) << 1;
        long af[4];
        #pragma unroll
        for (int ks = 0; ks < 4; ++ks) af[ks] = Al[r * 8 + ((ks * 2 + lkh) ^ xA)];
        #pragma unroll
        for (int tn = 0; tn < 4; ++tn) {
            const int n  = wn * 128 + tn * 32 + ln;
            const int xN = ((n >> 1) & 3) << 1;
            #pragma unroll
            for (int ks = 0; ks < 4; ++ks) {
                const long bf = Yl[n * 8 + ((ks * 2 + lkh) ^ xN)];
                acc[tn] = __builtin_amdgcn_mfma_f32_32x32x16_fp8_fp8(af[ks], bf, acc[tn], 0, 0, 0);
            }
        }
    }

    // epilogue: part = sum over held (64*W)[i][n] * Y[i][n]; scale 1/64 at end
    float part = 0.f;
    #pragma unroll
    for (int tn = 0; tn < 4; ++tn) {
        const int n = wn * 128 + tn * 32 + ln;
        #pragma unroll
        for (int rr = 0; rr < 16; ++rr) {
            const int i = I0 + wm * 32 + (rr & 3) + 8 * (rr >> 2) + 4 * lkh;
            part += acc[tn][rr] * (float)Yr[(size_t)i * Dd + n];
        }
    }
    #pragma unroll
    for (int off = 32; off > 0; off >>= 1) part += __shfl_down(part, off, 64);
    __shared__ float red[16];
    if (l == 0) red[w] = part;
    __syncthreads();
    if (threadIdx.x == 0) {
        float tt = 0.f;
        #pragma unroll
        for (int i = 0; i < 16; ++i) tt += red[i];
        atomicAdd(T, tt * 0.015625f);   // 1/64
    }
}

// ---------------------------------------------------------------------------
// K4: out[0] = homo = -T ; out[1] = hetero = ||s||^2 - T
__global__ __launch_bounds__(256) void k_final(const float* __restrict__ s,
                                               const float* __restrict__ T,
                                               float* __restrict__ out) {
    const int t = threadIdx.x;
    float v = s[t];
    float p = v * v;
    #pragma unroll
    for (int off = 32; off > 0; off >>= 1) p += __shfl_down(p, off, 64);
    __shared__ float red[4];
    if ((t & 63) == 0) red[t >> 6] = p;
    __syncthreads();
    if (t == 0) {
        const float ss = red[0] + red[1] + red[2] + red[3];
        const float Tv = *T;
        out[0] = -Tv;
        out[1] = ss - Tv;
    }
}

// ---------------------------------------------------------------------------
extern "C" void kernel_launch(void* const* d_in, const int* in_sizes, int n_in,
                              void* d_out, int out_size, void* d_ws, size_t ws_size,
                              hipStream_t stream) {
    const float* Z = (const float*)d_in[1];
    const float* A = (const float*)d_in[2];
    float* out = (float*)d_out;

    char* ws = (char*)d_ws;
    float*         dis  = (float*)(ws);                          // 32 KB
    float*         rd   = (float*)(ws + 32768);                  // 32 KB
    float*         s    = (float*)(ws + 65536);                  // 1 KB
    float*         T    = (float*)(ws + 66560);                  // 4 B
    _Float16*      Yr   = (_Float16*)(ws + 131072);              // 4 MB [8192][256]
    unsigned char* Ytf8 = (unsigned char*)(ws + 131072 + (size_t)Nn * Dd * 2);  // 2 MB
    unsigned char* Af8  = (unsigned char*)(ws + 131072 + (size_t)Nn * Dd * 3);  // 64 MB

    k_rowcvt<<<Nn / 4, 256, 0, stream>>>(A, Af8, dis, rd, s, T);
    k_makeYt<<<Nn / 64, 256, 0, stream>>>(Z, dis, Ytf8, Yr);
    k_colsum<<<Nn / 256, 256, 0, stream>>>(Yr, rd, s);
    k_main<<<(Nn / BM) * (Nn / KC), 1024, 0, stream>>>(Af8, Ytf8, Yr, T);
    k_final<<<1, 256, 0, stream>>>(s, T, out);
}